// Round 5
// baseline (270.732 us; speedup 1.0000x reference)
//
#include <hip/hip_runtime.h>
#include <math.h>

#define HIDDEN 768
#define NH 12
#define DH 64
#define SEQ 2048
#define BATCH 4

typedef __bf16 bf16;
typedef bf16 bf16x4 __attribute__((ext_vector_type(4)));
typedef bf16 bf16x8 __attribute__((ext_vector_type(8)));
typedef float f32x4 __attribute__((ext_vector_type(4)));

// ---------------------------------------------------------------------------
// prep_x: X fp32 -> Xb bf16 (8 elems/thread)
// ---------------------------------------------------------------------------
__global__ __launch_bounds__(256) void prep_x(const float* __restrict__ X,
                                              bf16* __restrict__ Xb) {
    const size_t i = ((size_t)blockIdx.x * 256 + threadIdx.x) * 8;
    float4 a = *(const float4*)(X + i);
    float4 b = *(const float4*)(X + i + 4);
    bf16x8 o = {(bf16)a.x, (bf16)a.y, (bf16)a.z, (bf16)a.w,
                (bf16)b.x, (bf16)b.y, (bf16)b.z, (bf16)b.w};
    *(bf16x8*)(Xb + i) = o;
}

// ---------------------------------------------------------------------------
// prep_w: transpose weights. z<3: Wq/Wk/Wv -> Wt bf16 [2304][768] (1-term).
// z==3: Wo -> Wot hi/lo bf16 [768][768].
// ---------------------------------------------------------------------------
__global__ __launch_bounds__(256) void prep_w(const float* __restrict__ Wq,
                                              const float* __restrict__ Wk,
                                              const float* __restrict__ Wv,
                                              const float* __restrict__ Wo,
                                              bf16* __restrict__ Wt,
                                              bf16* __restrict__ Wot_hi,
                                              bf16* __restrict__ Wot_lo) {
    __shared__ float Ts[64][68];
    const int tid = threadIdx.x;
    const int n0 = blockIdx.x * 64, k0 = blockIdx.y * 64, z = blockIdx.z;
    const float* W = (z == 0) ? Wq : (z == 1) ? Wk : (z == 2) ? Wv : Wo;

    {
        const int r = tid >> 2, c = (tid & 3) << 4;
        const float* src = W + (size_t)(k0 + r) * HIDDEN + n0 + c;
#pragma unroll
        for (int j = 0; j < 4; ++j)
            *(float4*)&Ts[r][c + 4 * j] = *(const float4*)(src + 4 * j);
    }
    __syncthreads();

    const int nl = tid >> 2, kc = (tid & 3) << 4;
    float v[16];
#pragma unroll
    for (int j = 0; j < 16; ++j) v[j] = Ts[kc + j][nl];

    if (z < 3) {
        bf16 hi[16];
#pragma unroll
        for (int j = 0; j < 16; ++j) hi[j] = (bf16)v[j];
        const size_t off = (size_t)(z * HIDDEN + n0 + nl) * HIDDEN + k0 + kc;
        *(bf16x8*)(Wt + off) = *(bf16x8*)&hi[0];
        *(bf16x8*)(Wt + off + 8) = *(bf16x8*)&hi[8];
    } else {
        bf16 hi[16], lo[16];
#pragma unroll
        for (int j = 0; j < 16; ++j) {
            hi[j] = (bf16)v[j];
            lo[j] = (bf16)(v[j] - (float)hi[j]);
        }
        const size_t off = (size_t)(n0 + nl) * HIDDEN + k0 + kc;
        *(bf16x8*)(Wot_hi + off) = *(bf16x8*)&hi[0];
        *(bf16x8*)(Wot_hi + off + 8) = *(bf16x8*)&hi[8];
        *(bf16x8*)(Wot_lo + off) = *(bf16x8*)&lo[0];
        *(bf16x8*)(Wot_lo + off + 8) = *(bf16x8*)&lo[8];
    }
}

// ---------------------------------------------------------------------------
// QKV GEMM, 1-term bf16, register-prefetch double buffer. 128x128 tile.
// MFMA 16x16x32 layouts (HW-verified R1-R4):
//   A: lane=A[m=l16][k=quad*8+j]; B: lane=B[k=quad*8+j][n=l16];
//   C/D: lane=D[row=quad*4+reg][col=l16]
// Q is pre-scaled by (1/sqrt(DH)) * log2(e) so attention can use native exp2.
// ---------------------------------------------------------------------------
__global__ __launch_bounds__(256) void gemm_qkv(
    const bf16* __restrict__ Xb, const bf16* __restrict__ Wt,
    const float* __restrict__ bq, const float* __restrict__ bk,
    const float* __restrict__ bv, bf16* __restrict__ q_out,
    bf16* __restrict__ k_out, bf16* __restrict__ v_out) {
    __shared__ bf16 As[128][40];
    __shared__ bf16 Bs[128][40];

    const int tid = threadIdx.x;
    const int ln = tid & 63, wv = tid >> 6;
    const int quad = ln >> 4, l16 = ln & 15;
    const int wm = wv >> 1, wn = wv & 1;
    const int n0 = blockIdx.x * 128, m0 = blockIdx.y * 128;

    f32x4 acc[4][4];
#pragma unroll
    for (int i = 0; i < 4; ++i)
#pragma unroll
        for (int j = 0; j < 4; ++j) acc[i][j] = (f32x4){0.f, 0.f, 0.f, 0.f};

    const int sr = tid >> 1, sc = (tid & 1) << 4;
    const bf16* gA = Xb + (size_t)(m0 + sr) * HIDDEN + sc;
    const bf16* gB = Wt + (size_t)(n0 + sr) * HIDDEN + sc;

    bf16x8 ar0, ar1, br0, br1;
    ar0 = *(const bf16x8*)gA;
    ar1 = *(const bf16x8*)(gA + 8);
    br0 = *(const bf16x8*)gB;
    br1 = *(const bf16x8*)(gB + 8);

    for (int k0 = 0; k0 < HIDDEN; k0 += 32) {
        __syncthreads();
        *(bf16x8*)&As[sr][sc] = ar0;
        *(bf16x8*)&As[sr][sc + 8] = ar1;
        *(bf16x8*)&Bs[sr][sc] = br0;
        *(bf16x8*)&Bs[sr][sc + 8] = br1;
        __syncthreads();
        if (k0 + 32 < HIDDEN) {
            ar0 = *(const bf16x8*)(gA + k0 + 32);
            ar1 = *(const bf16x8*)(gA + k0 + 40);
            br0 = *(const bf16x8*)(gB + k0 + 32);
            br1 = *(const bf16x8*)(gB + k0 + 40);
        }

        bf16x8 ah[4], bh[4];
#pragma unroll
        for (int i = 0; i < 4; ++i) {
            ah[i] = *(bf16x8*)&As[wm * 64 + i * 16 + l16][quad * 8];
            bh[i] = *(bf16x8*)&Bs[wn * 64 + i * 16 + l16][quad * 8];
        }
#pragma unroll
        for (int mi = 0; mi < 4; ++mi)
#pragma unroll
            for (int ni = 0; ni < 4; ++ni)
                acc[mi][ni] = __builtin_amdgcn_mfma_f32_16x16x32_bf16(
                    ah[mi], bh[ni], acc[mi][ni], 0, 0, 0);
    }

    const int nb = n0 + wn * 64;
    const int which = nb / HIDDEN;         // 0=Q, 1=K, 2=V
    const int nrel = nb - which * HIDDEN;  // = h*64
    const int h = nrel >> 6;

    if (which < 2) {
        // 0.125 * log2(e) = 0.18033688011112042  (exp2-based softmax)
        const float scale = (which == 0) ? 0.18033688011112042f : 1.0f;
        const float* bias = (which == 0) ? bq : bk;
        bf16* dst = (which == 0) ? q_out : k_out;
#pragma unroll
        for (int ni = 0; ni < 4; ++ni) {
            const int dh = ni * 16 + l16;
            const float bb = bias[nrel + dh];
#pragma unroll
            for (int mi = 0; mi < 4; ++mi)
#pragma unroll
                for (int r = 0; r < 4; ++r) {
                    const int m = m0 + wm * 64 + mi * 16 + quad * 4 + r;
                    const int bi = m >> 11, s = m & (SEQ - 1);
                    dst[(((size_t)(bi * NH + h) * SEQ + s) << 6) + dh] =
                        (bf16)(scale * (acc[mi][ni][r] + bb));
                }
        }
    } else {
        // V transposed: Vt[b][h][d][s]
        const int bi = m0 >> 11;
        const int sbase = (m0 & (SEQ - 1)) + wm * 64;
#pragma unroll
        for (int ni = 0; ni < 4; ++ni) {
            const int dh = ni * 16 + l16;
            const float bb = bv[nrel + dh];
            bf16* vrow = v_out + ((size_t)(bi * NH + h) * DH + dh) * SEQ;
#pragma unroll
            for (int mi = 0; mi < 4; ++mi) {
                bf16x4 pk = {(bf16)(acc[mi][ni][0] + bb),
                             (bf16)(acc[mi][ni][1] + bb),
                             (bf16)(acc[mi][ni][2] + bb),
                             (bf16)(acc[mi][ni][3] + bb)};
                *(bf16x4*)(vrow + sbase + mi * 16 + quad * 4) = pk;
            }
        }
    }
}

// ---------------------------------------------------------------------------
// MFMA flash attention, transposed orientation, no-max softmax (exp2-based;
// Q pre-scaled by 0.125*log2e). 4 waves; wave w owns queries w*32..w*32+31.
//
// ROUND-5: double-buffered K/V LDS -> ONE barrier per K-iteration (was 2).
// Old critical path per iter: barrier -> ds_write(+vmcnt) -> barrier ->
// QK -> softmax -> PV (2-phase stall structure, m233: stage+barrier is the
// dominant cost). New: compute on buf[cur] while writing prefetched tile
// kt+1 into buf[cur^1] (disjoint, no hazard); the single end-of-iter
// barrier orders BOTH write(kt+1) vs read(kt+1) AND read(cur) vs next
// overwrite of cur. 33 barriers/block instead of 64; stage ds_writes
// overlap PV-MFMA instead of serializing between two drains.
// Register-destination global prefetch loads cross __syncthreads without a
// vmcnt drain (gemm_qkv already relies on this).
// Ms[SEQ] dropped (8KB) to keep LDS at 48KB -> 3 blocks/CU (grid = 3/CU
// exactly); mask is prologue-only on the fastmask path, L2-resident.
// #pragma unroll 2 makes buffer indices compile-time static.
//
// XCD swizzle (R4, verified): wg%8 = XCD owns 6 complete (b,h) K/V planes
// (3MB < 4MB L2): FETCH 104MB -> 18.5MB.
// LDS XOR swizzle (R2, verified): col ^= (row&7)<<3 both sides, unpadded.
// ---------------------------------------------------------------------------
__global__ __launch_bounds__(256) void attn_mfma(const bf16* __restrict__ Q,
                                                 const bf16* __restrict__ K,
                                                 const bf16* __restrict__ Vt,
                                                 const float* __restrict__ mask,
                                                 float* __restrict__ ctx) {
    __shared__ bf16 Ks[2][64 * 64];
    __shared__ bf16 Vts[2][64 * 64];
    __shared__ bf16 Ps[128 * 64];
    __shared__ int allones_s;

    const int tid = threadIdx.x;
    const int ln = tid & 63, w = tid >> 6;
    const int quad = ln >> 4, l16 = ln & 15;

    // XCD-aware swizzle: wg%8 = XCD; give each XCD a contiguous logical range.
    const int wg = blockIdx.x;                      // 0..767
    const int logical = (wg & 7) * 96 + (wg >> 3);  // bijective (768%8==0)
    const int qt = logical & 15;
    const int h = (logical >> 4) % NH;
    const int b = logical / (16 * NH);

    const size_t bh = (size_t)b * NH + h;
    const bf16* Qp = Q + ((bh * SEQ + (size_t)qt * 128) << 6);
    const bf16* Kp = K + (bh * SEQ << 6);
    const bf16* Vp = Vt + (bh * DH) * SEQ;
    const float* mrow = mask + (size_t)b * SEQ;

    // block-uniform all-ones flag (mask read from global; L2-resident)
    if (tid == 0) allones_s = 1;
    {
        float4 m0 = *(const float4*)(mrow + tid * 8);
        float4 m1 = *(const float4*)(mrow + tid * 8 + 4);
        bool ok = (m0.x == 1.f) & (m0.y == 1.f) & (m0.z == 1.f) &
                  (m0.w == 1.f) & (m1.x == 1.f) & (m1.y == 1.f) &
                  (m1.z == 1.f) & (m1.w == 1.f);
        __syncthreads();
        if (!ok) allones_s = 0;  // benign race: all writers store 0
    }
    __syncthreads();
    const bool fastmask = (allones_s != 0);

    // Q frags (B-operand of S^T)
    bf16x8 qb[2][2];
#pragma unroll
    for (int qg = 0; qg < 2; ++qg)
#pragma unroll
        for (int hf = 0; hf < 2; ++hf)
            qb[qg][hf] = *(const bf16x8*)(Qp + ((w * 32 + qg * 16 + l16) << 6) +
                                          hf * 32 + quad * 8);
    float mq[2];
#pragma unroll
    for (int qg = 0; qg < 2; ++qg)
        mq[qg] = mrow[qt * 128 + w * 32 + qg * 16 + l16];

    float l_i[2] = {0.f, 0.f};  // lane-partial row sums (over this quad's keys)
    f32x4 acc[4][2];
#pragma unroll
    for (int fd = 0; fd < 4; ++fd)
#pragma unroll
        for (int qg = 0; qg < 2; ++qg) acc[fd][qg] = (f32x4){0.f, 0.f, 0.f, 0.f};

    // staging: 64 rows x 64 cols, swizzled col = c ^ ((row&7)<<3)
    const int sr = tid >> 2, sc = (tid & 3) << 4;
    const int ssw = (sr & 7) << 3;
    const int d0 = sc ^ ssw, d1 = (sc + 8) ^ ssw;
    const bf16* kbase = Kp + ((size_t)sr << 6) + sc;
    const bf16* vbase = Vp + (size_t)sr * SEQ + sc;

    const int NT = SEQ / 64;
    bf16x8 kr0, kr1, vr0, vr1;

    // prologue: tile 0 -> buf0; issue tile-1 loads; barrier
    kr0 = *(const bf16x8*)kbase;
    kr1 = *(const bf16x8*)(kbase + 8);
    vr0 = *(const bf16x8*)vbase;
    vr1 = *(const bf16x8*)(vbase + 8);
    *(bf16x8*)&Ks[0][sr * 64 + d0] = kr0;
    *(bf16x8*)&Ks[0][sr * 64 + d1] = kr1;
    *(bf16x8*)&Vts[0][sr * 64 + d0] = vr0;
    *(bf16x8*)&Vts[0][sr * 64 + d1] = vr1;
    kr0 = *(const bf16x8*)(kbase + 4096);
    kr1 = *(const bf16x8*)(kbase + 4096 + 8);
    vr0 = *(const bf16x8*)(vbase + 64);
    vr1 = *(const bf16x8*)(vbase + 64 + 8);
    __syncthreads();

    const int fsw = (l16 & 7) << 3;  // row&7 == l16&7 for rows f*16+l16

#pragma unroll 2
    for (int kt = 0; kt < NT; ++kt) {
        const int cur = kt & 1;

        // S^T = K.Q^T (reads buf[cur])
        f32x4 st[4][2];
#pragma unroll
        for (int f = 0; f < 4; ++f) {
            const int krow = (f * 16 + l16) * 64;
            bf16x8 ka0 = *(bf16x8*)&Ks[cur][krow + ((quad * 8) ^ fsw)];
            bf16x8 ka1 = *(bf16x8*)&Ks[cur][krow + ((32 + quad * 8) ^ fsw)];
#pragma unroll
            for (int qg = 0; qg < 2; ++qg) {
                f32x4 c = {0.f, 0.f, 0.f, 0.f};
                c = __builtin_amdgcn_mfma_f32_16x16x32_bf16(ka0, qb[qg][0], c, 0, 0, 0);
                c = __builtin_amdgcn_mfma_f32_16x16x32_bf16(ka1, qb[qg][1], c, 0, 0, 0);
                st[f][qg] = c;
            }
        }

        if (!fastmask) {
#pragma unroll
            for (int f = 0; f < 4; ++f) {
                const float4 mk4 =
                    *(const float4*)(mrow + kt * 64 + f * 16 + quad * 4);
                const float mkk[4] = {mk4.x, mk4.y, mk4.z, mk4.w};
#pragma unroll
                for (int qg = 0; qg < 2; ++qg)
#pragma unroll
                    for (int r = 0; r < 4; ++r) {
                        const float ext = mq[qg] * mkk[r];
                        // st is in log2 domain: 1e9*log2e = 1.4427e9
                        st[f][qg][r] =
                            ext * st[f][qg][r] - (1.0f - ext) * 1.4426950e9f;
                    }
            }
        }

        // exp2 (no shift), lane-partial sums, pack P into swizzled Ps
#pragma unroll
        for (int qg = 0; qg < 2; ++qg) {
            const int row = w * 32 + qg * 16 + l16;
            const int sw = (row & 7) << 3;
            bf16* prow = &Ps[row * 64];
#pragma unroll
            for (int f = 0; f < 4; ++f) {
                float p0 = __builtin_amdgcn_exp2f(st[f][qg][0]);
                float p1 = __builtin_amdgcn_exp2f(st[f][qg][1]);
                float p2 = __builtin_amdgcn_exp2f(st[f][qg][2]);
                float p3 = __builtin_amdgcn_exp2f(st[f][qg][3]);
                l_i[qg] += (p0 + p1) + (p2 + p3);
                bf16x4 pk = {(bf16)p0, (bf16)p1, (bf16)p2, (bf16)p3};
                *(bf16x4*)&prow[(f * 16 + quad * 4) ^ sw] = pk;
            }
        }

        // P^T frags back (Ps rows wave-local: no barrier)
        bf16x8 pb[2][2];
#pragma unroll
        for (int qg = 0; qg < 2; ++qg) {
            const int row = w * 32 + qg * 16 + l16;
            const int sw = (row & 7) << 3;
#pragma unroll
            for (int hf = 0; hf < 2; ++hf)
                pb[qg][hf] =
                    *(bf16x8*)&Ps[row * 64 + ((hf * 32 + quad * 8) ^ sw)];
        }

        // stage tile kt+1 into buf[cur^1] (disjoint from buf[cur] readers;
        // vmcnt wait on loads issued one full iteration ago), then issue
        // loads for tile kt+2. Overlaps with the PV MFMAs below.
        if (kt + 1 < NT) {
            *(bf16x8*)&Ks[cur ^ 1][sr * 64 + d0] = kr0;
            *(bf16x8*)&Ks[cur ^ 1][sr * 64 + d1] = kr1;
            *(bf16x8*)&Vts[cur ^ 1][sr * 64 + d0] = vr0;
            *(bf16x8*)&Vts[cur ^ 1][sr * 64 + d1] = vr1;
            if (kt + 2 < NT) {
                kr0 = *(const bf16x8*)(kbase + ((size_t)(kt + 2) << 12));
                kr1 = *(const bf16x8*)(kbase + ((size_t)(kt + 2) << 12) + 8);
                vr0 = *(const bf16x8*)(vbase + (kt + 2) * 64);
                vr1 = *(const bf16x8*)(vbase + (kt + 2) * 64 + 8);
            }
        }

        // O^T += V^T.P^T (reads buf[cur])
#pragma unroll
        for (int fd = 0; fd < 4; ++fd) {
            const int vrow = (fd * 16 + l16) * 64;
            bf16x8 va0 = *(bf16x8*)&Vts[cur][vrow + ((quad * 8) ^ fsw)];
            bf16x8 va1 = *(bf16x8*)&Vts[cur][vrow + ((32 + quad * 8) ^ fsw)];
#pragma unroll
            for (int qg = 0; qg < 2; ++qg) {
                f32x4 c = acc[fd][qg];
                c = __builtin_amdgcn_mfma_f32_16x16x32_bf16(va0, pb[qg][0], c, 0, 0, 0);
                c = __builtin_amdgcn_mfma_f32_16x16x32_bf16(va1, pb[qg][1], c, 0, 0, 0);
                acc[fd][qg] = c;
            }
        }

        // single barrier: orders write(kt+1) vs read(kt+1) AND
        // read(cur) vs its overwrite in iter kt+1.
        if (kt + 1 < NT) __syncthreads();
    }

    // final row-sum reduction across quads (query id = l16 only)
#pragma unroll
    for (int qg = 0; qg < 2; ++qg) {
        l_i[qg] += __shfl_xor(l_i[qg], 16);
        l_i[qg] += __shfl_xor(l_i[qg], 32);
    }

    // epilogue: ctx fp32 [B*S][768]
#pragma unroll
    for (int qg = 0; qg < 2; ++qg) {
        const float inv = 1.0f / l_i[qg];
        const size_t row = (size_t)b * SEQ + qt * 128 + w * 32 + qg * 16 + l16;
#pragma unroll
        for (int fd = 0; fd < 4; ++fd) {
            float4 o = {acc[fd][qg][0] * inv, acc[fd][qg][1] * inv,
                        acc[fd][qg][2] * inv, acc[fd][qg][3] * inv};
            *(float4*)(ctx + row * HIDDEN + h * 64 + fd * 16 + quad * 4) = o;
        }
    }
}

// ---------------------------------------------------------------------------
// Output GEMM, 3-term split, 128m x 64n tile (grid 768 = 3 blocks/CU),
// register prefetch. A = ctx fp32 (hi/lo split during staging), B = Wot.
// Waves 2x2: wave covers 64m x 32n; frags 4m x 2n.
// ---------------------------------------------------------------------------
__global__ __launch_bounds__(256) void gemm_out(const float* __restrict__ ctx,
                                                const bf16* __restrict__ Bhi,
                                                const bf16* __restrict__ Blo,
                                                const float* __restrict__ bo,
                                                float* __restrict__ fout) {
    __shared__ bf16 As_hi[128][40];
    __shared__ bf16 As_lo[128][40];
    __shared__ bf16 Bs_hi[64][40];
    __shared__ bf16 Bs_lo[64][40];

    const int tid = threadIdx.x;
    const int ln = tid & 63, wv = tid >> 6;
    const int quad = ln >> 4, l16 = ln & 15;
    const int wm = wv >> 1, wn = wv & 1;
    const int n0 = blockIdx.x * 64, m0 = blockIdx.y * 128;

    f32x4 acc[4][2];
#pragma unroll
    for (int i = 0; i < 4; ++i)
#pragma unroll
        for (int j = 0; j < 2; ++j) acc[i][j] = (f32x4){0.f, 0.f, 0.f, 0.f};

    const int sra = tid >> 1, sca = (tid & 1) << 4;  // A: 128 rows x 32 cols
    const int srb = tid >> 2, scb = (tid & 3) << 3;  // B: 64 rows x 32 cols
    const float* gA = ctx + (size_t)(m0 + sra) * HIDDEN + sca;
    const bf16* gBh = Bhi + (size_t)(n0 + srb) * HIDDEN + scb;
    const bf16* gBl = Blo + (size_t)(n0 + srb) * HIDDEN + scb;

    float fa[16];
    bf16x8 brh, brl;
#pragma unroll
    for (int j = 0; j < 4; ++j) *(float4*)&fa[4 * j] = *(const float4*)(gA + 4 * j);
    brh = *(const bf16x8*)gBh;
    brl = *(const bf16x8*)gBl;

    for (int k0 = 0; k0 < HIDDEN; k0 += 32) {
        bf16 hi[16], lo[16];
#pragma unroll
        for (int j = 0; j < 16; ++j) {
            hi[j] = (bf16)fa[j];
            lo[j] = (bf16)(fa[j] - (float)hi[j]);
        }
        __syncthreads();
        *(bf16x8*)&As_hi[sra][sca] = *(bf16x8*)&hi[0];
        *(bf16x8*)&As_hi[sra][sca + 8] = *(bf16x8*)&hi[8];
        *(bf16x8*)&As_lo[sra][sca] = *(bf16x8*)&lo[0];
        *(bf16x8*)&As_lo[sra][sca + 8] = *(bf16x8*)&lo[8];
        *(bf16x8*)&Bs_hi[srb][scb] = brh;
        *(bf16x8*)&Bs_lo[srb][scb] = brl;
        __syncthreads();
        if (k0 + 32 < HIDDEN) {
#pragma unroll
            for (int j = 0; j < 4; ++j)
                *(float4*)&fa[4 * j] = *(const float4*)(gA + k0 + 32 + 4 * j);
            brh = *(const bf16x8*)(gBh + k0 + 32);
            brl = *(const bf16x8*)(gBl + k0 + 32);
        }

        bf16x8 ah[4], al[4], bh[2], bl[2];
#pragma unroll
        for (int i = 0; i < 4; ++i) {
            ah[i] = *(bf16x8*)&As_hi[wm * 64 + i * 16 + l16][quad * 8];
            al[i] = *(bf16x8*)&As_lo[wm * 64 + i * 16 + l16][quad * 8];
        }
#pragma unroll
        for (int i = 0; i < 2; ++i) {
            bh[i] = *(bf16x8*)&Bs_hi[wn * 32 + i * 16 + l16][quad * 8];
            bl[i] = *(bf16x8*)&Bs_lo[wn * 32 + i * 16 + l16][quad * 8];
        }
#pragma unroll
        for (int mi = 0; mi < 4; ++mi)
#pragma unroll
            for (int ni = 0; ni < 2; ++ni) {
                f32x4 c = acc[mi][ni];
                c = __builtin_amdgcn_mfma_f32_16x16x32_bf16(ah[mi], bh[ni], c, 0, 0, 0);
                c = __builtin_amdgcn_mfma_f32_16x16x32_bf16(ah[mi], bl[ni], c, 0, 0, 0);
                c = __builtin_amdgcn_mfma_f32_16x16x32_bf16(al[mi], bh[ni], c, 0, 0, 0);
                acc[mi][ni] = c;
            }
    }

#pragma unroll
    for (int ni = 0; ni < 2; ++ni) {
        const int n = n0 + wn * 32 + ni * 16 + l16;
        const float bb = bo[n];
#pragma unroll
        for (int mi = 0; mi < 4; ++mi)
#pragma unroll
            for (int r = 0; r < 4; ++r) {
                const int m = m0 + wm * 64 + mi * 16 + quad * 4 + r;
                float x = acc[mi][ni][r] + bb;
                x = 0.5f * x * (1.0f + erff(x * 0.70710678118654752440f));
                fout[(size_t)m * HIDDEN + n] = x;
            }
    }
}

// ---------------------------------------------------------------------------
extern "C" void kernel_launch(void* const* d_in, const int* in_sizes, int n_in,
                              void* d_out, int out_size, void* d_ws, size_t ws_size,
                              hipStream_t stream) {
    const float* X    = (const float*)d_in[0];
    const float* mask = (const float*)d_in[1];
    const float* Wq   = (const float*)d_in[2];
    const float* bq   = (const float*)d_in[3];
    const float* Wk   = (const float*)d_in[4];
    const float* bk   = (const float*)d_in[5];
    const float* Wv   = (const float*)d_in[6];
    const float* bv   = (const float*)d_in[7];
    const float* Wo   = (const float*)d_in[8];
    const float* bo   = (const float*)d_in[9];
    float* out = (float*)d_out;

    char* w = (char*)d_ws;
    const size_t NE = (size_t)BATCH * SEQ * HIDDEN;  // 6.29M elems
    bf16* q_ws   = (bf16*)w;  w += NE * 2;
    bf16* k_ws   = (bf16*)w;  w += NE * 2;
    bf16* vt_ws  = (bf16*)w;  w += NE * 2;
    float* ctx   = (float*)w; w += NE * 4;
    bf16* Xb     = (bf16*)w;  w += NE * 2;
    bf16* Wt     = (bf16*)w;  w += (size_t)3 * HIDDEN * HIDDEN * 2;
    bf16* Wot_hi = (bf16*)w;  w += (size_t)HIDDEN * HIDDEN * 2;
    bf16* Wot_lo = (bf16*)w;  w += (size_t)HIDDEN * HIDDEN * 2;

    prep_x<<<(int)(NE / 2048), 256, 0, stream>>>(X, Xb);
    prep_w<<<dim3(12, 12, 4), 256, 0, stream>>>(Wq, Wk, Wv, Wo, Wt, Wot_hi,
                                                Wot_lo);
    gemm_qkv<<<dim3(18, 64), 256, 0, stream>>>(Xb, Wt, bq, bk, bv, q_ws, k_ws,
                                               vt_ws);
    attn_mfma<<<dim3(16 * NH * BATCH), 256, 0, stream>>>(q_ws, k_ws, vt_ws,
                                                         mask, ctx);
    gemm_out<<<dim3(12, 64), 256, 0, stream>>>(ctx, Wot_hi, Wot_lo, bo, out);
}

// Round 6
// 263.114 us; speedup vs baseline: 1.0290x; 1.0290x over previous
//
#include <hip/hip_runtime.h>
#include <math.h>

#define HIDDEN 768
#define NH 12
#define DH 64
#define SEQ 2048
#define BATCH 4

typedef __bf16 bf16;
typedef bf16 bf16x4 __attribute__((ext_vector_type(4)));
typedef bf16 bf16x8 __attribute__((ext_vector_type(8)));
typedef float f32x4 __attribute__((ext_vector_type(4)));

// global_load_lds dwordx4: per-lane global src, wave-uniform LDS base,
// HW writes lane i at base + i*16 (m97/m103: +35% over reg-staging at 128^2).
__device__ __forceinline__ void load_lds16(const void* g, void* l) {
    __builtin_amdgcn_global_load_lds(
        (__attribute__((address_space(1))) void*)g,
        (__attribute__((address_space(3))) void*)l, 16, 0, 0);
}

// ---------------------------------------------------------------------------
// prep_x: X fp32 -> Xb bf16 (8 elems/thread)
// ---------------------------------------------------------------------------
__global__ __launch_bounds__(256) void prep_x(const float* __restrict__ X,
                                              bf16* __restrict__ Xb) {
    const size_t i = ((size_t)blockIdx.x * 256 + threadIdx.x) * 8;
    float4 a = *(const float4*)(X + i);
    float4 b = *(const float4*)(X + i + 4);
    bf16x8 o = {(bf16)a.x, (bf16)a.y, (bf16)a.z, (bf16)a.w,
                (bf16)b.x, (bf16)b.y, (bf16)b.z, (bf16)b.w};
    *(bf16x8*)(Xb + i) = o;
}

// ---------------------------------------------------------------------------
// prep_w: transpose weights. z<3: Wq/Wk/Wv -> Wt bf16 [2304][768] (1-term).
// z==3: Wo -> Wot hi/lo bf16 [768][768].
// ---------------------------------------------------------------------------
__global__ __launch_bounds__(256) void prep_w(const float* __restrict__ Wq,
                                              const float* __restrict__ Wk,
                                              const float* __restrict__ Wv,
                                              const float* __restrict__ Wo,
                                              bf16* __restrict__ Wt,
                                              bf16* __restrict__ Wot_hi,
                                              bf16* __restrict__ Wot_lo) {
    __shared__ float Ts[64][68];
    const int tid = threadIdx.x;
    const int n0 = blockIdx.x * 64, k0 = blockIdx.y * 64, z = blockIdx.z;
    const float* W = (z == 0) ? Wq : (z == 1) ? Wk : (z == 2) ? Wv : Wo;

    {
        const int r = tid >> 2, c = (tid & 3) << 4;
        const float* src = W + (size_t)(k0 + r) * HIDDEN + n0 + c;
#pragma unroll
        for (int j = 0; j < 4; ++j)
            *(float4*)&Ts[r][c + 4 * j] = *(const float4*)(src + 4 * j);
    }
    __syncthreads();

    const int nl = tid >> 2, kc = (tid & 3) << 4;
    float v[16];
#pragma unroll
    for (int j = 0; j < 16; ++j) v[j] = Ts[kc + j][nl];

    if (z < 3) {
        bf16 hi[16];
#pragma unroll
        for (int j = 0; j < 16; ++j) hi[j] = (bf16)v[j];
        const size_t off = (size_t)(z * HIDDEN + n0 + nl) * HIDDEN + k0 + kc;
        *(bf16x8*)(Wt + off) = *(bf16x8*)&hi[0];
        *(bf16x8*)(Wt + off + 8) = *(bf16x8*)&hi[8];
    } else {
        bf16 hi[16], lo[16];
#pragma unroll
        for (int j = 0; j < 16; ++j) {
            hi[j] = (bf16)v[j];
            lo[j] = (bf16)(v[j] - (float)hi[j]);
        }
        const size_t off = (size_t)(n0 + nl) * HIDDEN + k0 + kc;
        *(bf16x8*)(Wot_hi + off) = *(bf16x8*)&hi[0];
        *(bf16x8*)(Wot_hi + off + 8) = *(bf16x8*)&hi[8];
        *(bf16x8*)(Wot_lo + off) = *(bf16x8*)&lo[0];
        *(bf16x8*)(Wot_lo + off + 8) = *(bf16x8*)&lo[8];
    }
}

// ---------------------------------------------------------------------------
// QKV GEMM — ROUND-6 REWRITE to the m97 structure (874 TF-verified shape):
// 128x128 tile, BK=64 (12 K-steps), LINEAR unpadded LDS [128][64] staged via
// global_load_lds dwordx4 (no VGPR round-trip, no staging VALU), 2 barriers
// per K-step (compiler drains vmcnt before the 2nd barrier).
//
// Swizzle discipline (rule 21: both sides or neither): gload_lds writes
// linearly (lane i at base+i*16), so the SOURCE global address carries the
// XOR: lane reads global bytecol ^ ((row&7)<<4) of its 128-B row chunk
// (permutes 16B blocks within the chunk -> coalescing preserved), and the
// ds_read fragment address applies the same XOR. Bank check for the b128
// fragment read (row = *,l16; byte col = h*64+quad*16): group =
// 16h + 4*(quad ^ (l16&7)) -> all 32 banks, only l16 vs l16+8 alias (2-way,
// free per m136).
//
// MFMA 16x16x32 layouts (HW-verified R1-R4):
//   A: lane=A[m=l16][k=quad*8+j]; B: lane=B[k=quad*8+j][n=l16];
//   C/D: lane=D[row=quad*4+reg][col=l16]
// Q is pre-scaled by (1/sqrt(DH)) * log2(e) so attention can use native exp2.
// ---------------------------------------------------------------------------
__global__ __launch_bounds__(256) void gemm_qkv(
    const bf16* __restrict__ Xb, const bf16* __restrict__ Wt,
    const float* __restrict__ bq, const float* __restrict__ bk,
    const float* __restrict__ bv, bf16* __restrict__ q_out,
    bf16* __restrict__ k_out, bf16* __restrict__ v_out) {
    __shared__ bf16 As[128 * 64];  // linear; holds source-swizzled content
    __shared__ bf16 Bs[128 * 64];

    const int tid = threadIdx.x;
    const int ln = tid & 63, wv = tid >> 6;
    const int quad = ln >> 4, l16 = ln & 15;
    const int wm = wv >> 1, wn = wv & 1;
    const int n0 = blockIdx.x * 128, m0 = blockIdx.y * 128;

    f32x4 acc[4][4];
#pragma unroll
    for (int i = 0; i < 4; ++i)
#pragma unroll
        for (int j = 0; j < 4; ++j) acc[i][j] = (f32x4){0.f, 0.f, 0.f, 0.f};

    // staging geometry: wave wv stages rows [wv*32, wv*32+32), 4 instrs of
    // 8 rows each; lane ln -> row sub-offset r8 = ln>>3, byte col (ln&7)*16,
    // source col XOR'd by r8<<4 (row&7 == r8 for all j since j*8, wv*32
    // don't touch bits 0..2).
    const int r8 = ln >> 3;
    const int bcol_sw = ((ln & 7) << 4) ^ (r8 << 4);
    const char* gA =
        (const char*)Xb + ((size_t)(m0 + wv * 32 + r8) * HIDDEN) * 2 + bcol_sw;
    const char* gB =
        (const char*)Wt + ((size_t)(n0 + wv * 32 + r8) * HIDDEN) * 2 + bcol_sw;
    bf16* As_w = As + (wv * 32) * 64;
    bf16* Bs_w = Bs + (wv * 32) * 64;

    const int fsw = (l16 & 7) << 4;  // fragment byte-swizzle (row&7 == l16&7)

    for (int k0 = 0; k0 < HIDDEN; k0 += 64) {
        __syncthreads();  // readers of previous tile done
#pragma unroll
        for (int j = 0; j < 4; ++j) {
            load_lds16(gA + (size_t)k0 * 2 + (size_t)j * (8 * HIDDEN * 2),
                       As_w + j * 8 * 64);
            load_lds16(gB + (size_t)k0 * 2 + (size_t)j * (8 * HIDDEN * 2),
                       Bs_w + j * 8 * 64);
        }
        __syncthreads();  // vmcnt(0) drain: tile resident

        bf16x8 ah[4][2], bh[4][2];
#pragma unroll
        for (int i = 0; i < 4; ++i) {
            const char* ra = (const char*)As + (wm * 64 + i * 16 + l16) * 128;
            const char* rb = (const char*)Bs + (wn * 64 + i * 16 + l16) * 128;
            ah[i][0] = *(const bf16x8*)(ra + ((quad * 16) ^ fsw));
            ah[i][1] = *(const bf16x8*)(ra + ((64 + quad * 16) ^ fsw));
            bh[i][0] = *(const bf16x8*)(rb + ((quad * 16) ^ fsw));
            bh[i][1] = *(const bf16x8*)(rb + ((64 + quad * 16) ^ fsw));
        }
#pragma unroll
        for (int mi = 0; mi < 4; ++mi)
#pragma unroll
            for (int ni = 0; ni < 4; ++ni) {
                f32x4 c = acc[mi][ni];
                c = __builtin_amdgcn_mfma_f32_16x16x32_bf16(ah[mi][0], bh[ni][0],
                                                            c, 0, 0, 0);
                c = __builtin_amdgcn_mfma_f32_16x16x32_bf16(ah[mi][1], bh[ni][1],
                                                            c, 0, 0, 0);
                acc[mi][ni] = c;
            }
    }

    const int nb = n0 + wn * 64;
    const int which = nb / HIDDEN;         // 0=Q, 1=K, 2=V
    const int nrel = nb - which * HIDDEN;  // = h*64
    const int h = nrel >> 6;

    if (which < 2) {
        // 0.125 * log2(e) = 0.18033688011112042  (exp2-based softmax)
        const float scale = (which == 0) ? 0.18033688011112042f : 1.0f;
        const float* bias = (which == 0) ? bq : bk;
        bf16* dst = (which == 0) ? q_out : k_out;
#pragma unroll
        for (int ni = 0; ni < 4; ++ni) {
            const int dh = ni * 16 + l16;
            const float bb = bias[nrel + dh];
#pragma unroll
            for (int mi = 0; mi < 4; ++mi)
#pragma unroll
                for (int r = 0; r < 4; ++r) {
                    const int m = m0 + wm * 64 + mi * 16 + quad * 4 + r;
                    const int bi = m >> 11, s = m & (SEQ - 1);
                    dst[(((size_t)(bi * NH + h) * SEQ + s) << 6) + dh] =
                        (bf16)(scale * (acc[mi][ni][r] + bb));
                }
        }
    } else {
        // V transposed: Vt[b][h][d][s]
        const int bi = m0 >> 11;
        const int sbase = (m0 & (SEQ - 1)) + wm * 64;
#pragma unroll
        for (int ni = 0; ni < 4; ++ni) {
            const int dh = ni * 16 + l16;
            const float bb = bv[nrel + dh];
            bf16* vrow = v_out + ((size_t)(bi * NH + h) * DH + dh) * SEQ;
#pragma unroll
            for (int mi = 0; mi < 4; ++mi) {
                bf16x4 pk = {(bf16)(acc[mi][ni][0] + bb),
                             (bf16)(acc[mi][ni][1] + bb),
                             (bf16)(acc[mi][ni][2] + bb),
                             (bf16)(acc[mi][ni][3] + bb)};
                *(bf16x4*)(vrow + sbase + mi * 16 + quad * 4) = pk;
            }
        }
    }
}

// ---------------------------------------------------------------------------
// MFMA flash attention — exact R4 configuration (best measured: 84.9us).
// 2-phase single-buffer staging (R5 dbuf was neutral-negative: implicit
// wave-level overlap at 3 blocks/CU already captures the pipelining).
// XCD swizzle (R4): FETCH 104MB -> 18.5MB. LDS XOR swizzle (R2). No setprio.
// ---------------------------------------------------------------------------
__global__ __launch_bounds__(256) void attn_mfma(const bf16* __restrict__ Q,
                                                 const bf16* __restrict__ K,
                                                 const bf16* __restrict__ Vt,
                                                 const float* __restrict__ mask,
                                                 float* __restrict__ ctx) {
    __shared__ bf16 Ks[64 * 64];
    __shared__ bf16 Vts[64 * 64];
    __shared__ bf16 Ps[128 * 64];
    __shared__ float Ms[SEQ];
    __shared__ int allones_s;

    const int tid = threadIdx.x;
    const int ln = tid & 63, w = tid >> 6;
    const int quad = ln >> 4, l16 = ln & 15;

    // XCD-aware swizzle: wg%8 = XCD; give each XCD a contiguous logical range.
    const int wg = blockIdx.x;                      // 0..767
    const int logical = (wg & 7) * 96 + (wg >> 3);  // bijective (768%8==0)
    const int qt = logical & 15;
    const int h = (logical >> 4) % NH;
    const int b = logical / (16 * NH);

    const size_t bh = (size_t)b * NH + h;
    const bf16* Qp = Q + ((bh * SEQ + (size_t)qt * 128) << 6);
    const bf16* Kp = K + (bh * SEQ << 6);
    const bf16* Vp = Vt + (bh * DH) * SEQ;

    // cache mask row, compute block-uniform all-ones flag
    if (tid == 0) allones_s = 1;
    {
        float4 m0 = *(const float4*)(mask + (size_t)b * SEQ + tid * 8);
        float4 m1 = *(const float4*)(mask + (size_t)b * SEQ + tid * 8 + 4);
        *(float4*)&Ms[tid * 8] = m0;
        *(float4*)&Ms[tid * 8 + 4] = m1;
        bool ok = (m0.x == 1.f) & (m0.y == 1.f) & (m0.z == 1.f) &
                  (m0.w == 1.f) & (m1.x == 1.f) & (m1.y == 1.f) &
                  (m1.z == 1.f) & (m1.w == 1.f);
        __syncthreads();
        if (!ok) allones_s = 0;  // benign race: all writers store 0
    }
    __syncthreads();
    const bool fastmask = (allones_s != 0);

    // Q frags (B-operand of S^T)
    bf16x8 qb[2][2];
#pragma unroll
    for (int qg = 0; qg < 2; ++qg)
#pragma unroll
        for (int hf = 0; hf < 2; ++hf)
            qb[qg][hf] = *(const bf16x8*)(Qp + ((w * 32 + qg * 16 + l16) << 6) +
                                          hf * 32 + quad * 8);
    float mq[2];
#pragma unroll
    for (int qg = 0; qg < 2; ++qg)
        mq[qg] = Ms[qt * 128 + w * 32 + qg * 16 + l16];

    float l_i[2] = {0.f, 0.f};  // lane-partial row sums (over this quad's keys)
    f32x4 acc[4][2];
#pragma unroll
    for (int fd = 0; fd < 4; ++fd)
#pragma unroll
        for (int qg = 0; qg < 2; ++qg) acc[fd][qg] = (f32x4){0.f, 0.f, 0.f, 0.f};

    // staging: 64 rows x 64 cols, swizzled col = c ^ ((row&7)<<3)
    const int sr = tid >> 2, sc = (tid & 3) << 4;
    const int ssw = (sr & 7) << 3;
    const int d0 = sc ^ ssw, d1 = (sc + 8) ^ ssw;
    const bf16* kbase = Kp + ((size_t)sr << 6) + sc;
    const bf16* vbase = Vp + (size_t)sr * SEQ + sc;

    bf16x8 kr0, kr1, vr0, vr1;
    kr0 = *(const bf16x8*)kbase;
    kr1 = *(const bf16x8*)(kbase + 8);
    vr0 = *(const bf16x8*)vbase;
    vr1 = *(const bf16x8*)(vbase + 8);

    for (int kt = 0; kt < SEQ / 64; ++kt) {
        __syncthreads();  // readers of tile kt-1 done
        *(bf16x8*)&Ks[sr * 64 + d0] = kr0;
        *(bf16x8*)&Ks[sr * 64 + d1] = kr1;
        *(bf16x8*)&Vts[sr * 64 + d0] = vr0;
        *(bf16x8*)&Vts[sr * 64 + d1] = vr1;
        __syncthreads();
        if (kt + 1 < SEQ / 64) {
            kr0 = *(const bf16x8*)(kbase + ((size_t)(kt + 1) << 12));
            kr1 = *(const bf16x8*)(kbase + ((size_t)(kt + 1) << 12) + 8);
            vr0 = *(const bf16x8*)(vbase + (kt + 1) * 64);
            vr1 = *(const bf16x8*)(vbase + (kt + 1) * 64 + 8);
        }

        // S^T = K.Q^T
        const int fsw = (l16 & 7) << 3;  // row&7 == l16&7 for rows f*16+l16
        f32x4 st[4][2];
#pragma unroll
        for (int f = 0; f < 4; ++f) {
            const int krow = (f * 16 + l16) * 64;
            bf16x8 ka0 = *(bf16x8*)&Ks[krow + ((quad * 8) ^ fsw)];
            bf16x8 ka1 = *(bf16x8*)&Ks[krow + ((32 + quad * 8) ^ fsw)];
#pragma unroll
            for (int qg = 0; qg < 2; ++qg) {
                f32x4 c = {0.f, 0.f, 0.f, 0.f};
                c = __builtin_amdgcn_mfma_f32_16x16x32_bf16(ka0, qb[qg][0], c, 0, 0, 0);
                c = __builtin_amdgcn_mfma_f32_16x16x32_bf16(ka1, qb[qg][1], c, 0, 0, 0);
                st[f][qg] = c;
            }
        }

        if (!fastmask) {
#pragma unroll
            for (int f = 0; f < 4; ++f) {
                const float4 mk4 = *(const float4*)&Ms[kt * 64 + f * 16 + quad * 4];
                const float mkk[4] = {mk4.x, mk4.y, mk4.z, mk4.w};
#pragma unroll
                for (int qg = 0; qg < 2; ++qg)
#pragma unroll
                    for (int r = 0; r < 4; ++r) {
                        const float ext = mq[qg] * mkk[r];
                        // st is in log2 domain: 1e9*log2e = 1.4427e9
                        st[f][qg][r] =
                            ext * st[f][qg][r] - (1.0f - ext) * 1.4426950e9f;
                    }
            }
        }

        // exp2 (no shift), lane-partial sums, pack P into swizzled Ps
#pragma unroll
        for (int qg = 0; qg < 2; ++qg) {
            const int row = w * 32 + qg * 16 + l16;
            const int sw = (row & 7) << 3;
            bf16* prow = &Ps[row * 64];
#pragma unroll
            for (int f = 0; f < 4; ++f) {
                float p0 = __builtin_amdgcn_exp2f(st[f][qg][0]);
                float p1 = __builtin_amdgcn_exp2f(st[f][qg][1]);
                float p2 = __builtin_amdgcn_exp2f(st[f][qg][2]);
                float p3 = __builtin_amdgcn_exp2f(st[f][qg][3]);
                l_i[qg] += (p0 + p1) + (p2 + p3);
                bf16x4 pk = {(bf16)p0, (bf16)p1, (bf16)p2, (bf16)p3};
                *(bf16x4*)&prow[(f * 16 + quad * 4) ^ sw] = pk;
            }
        }

        // O^T += V^T.P^T (Ps rows wave-local: no barrier)
        bf16x8 pb[2][2];
#pragma unroll
        for (int qg = 0; qg < 2; ++qg) {
            const int row = w * 32 + qg * 16 + l16;
            const int sw = (row & 7) << 3;
#pragma unroll
            for (int hf = 0; hf < 2; ++hf)
                pb[qg][hf] =
                    *(bf16x8*)&Ps[row * 64 + ((hf * 32 + quad * 8) ^ sw)];
        }
#pragma unroll
        for (int fd = 0; fd < 4; ++fd) {
            const int vrow = (fd * 16 + l16) * 64;
            bf16x8 va0 = *(bf16x8*)&Vts[vrow + ((quad * 8) ^ fsw)];
            bf16x8 va1 = *(bf16x8*)&Vts[vrow + ((32 + quad * 8) ^ fsw)];
#pragma unroll
            for (int qg = 0; qg < 2; ++qg) {
                f32x4 c = acc[fd][qg];
                c = __builtin_amdgcn_mfma_f32_16x16x32_bf16(va0, pb[qg][0], c, 0, 0, 0);
                c = __builtin_amdgcn_mfma_f32_16x16x32_bf16(va1, pb[qg][1], c, 0, 0, 0);
                acc[fd][qg] = c;
            }
        }
    }

    // final row-sum reduction across quads (query id = l16 only)
#pragma unroll
    for (int qg = 0; qg < 2; ++qg) {
        l_i[qg] += __shfl_xor(l_i[qg], 16);
        l_i[qg] += __shfl_xor(l_i[qg], 32);
    }

    // epilogue: ctx fp32 [B*S][768]
#pragma unroll
    for (int qg = 0; qg < 2; ++qg) {
        const float inv = 1.0f / l_i[qg];
        const size_t row = (size_t)b * SEQ + qt * 128 + w * 32 + qg * 16 + l16;
#pragma unroll
        for (int fd = 0; fd < 4; ++fd) {
            float4 o = {acc[fd][qg][0] * inv, acc[fd][qg][1] * inv,
                        acc[fd][qg][2] * inv, acc[fd][qg][3] * inv};
            *(float4*)(ctx + row * HIDDEN + h * 64 + fd * 16 + quad * 4) = o;
        }
    }
}

// ---------------------------------------------------------------------------
// Output GEMM, 3-term split, 128m x 64n tile (grid 768 = 3 blocks/CU),
// register prefetch. A = ctx fp32 (hi/lo split during staging), B = Wot.
// Waves 2x2: wave covers 64m x 32n; frags 4m x 2n.
// ---------------------------------------------------------------------------
__global__ __launch_bounds__(256) void gemm_out(const float* __restrict__ ctx,
                                                const bf16* __restrict__ Bhi,
                                                const bf16* __restrict__ Blo,
                                                const float* __restrict__ bo,
                                                float* __restrict__ fout) {
    __shared__ bf16 As_hi[128][40];
    __shared__ bf16 As_lo[128][40];
    __shared__ bf16 Bs_hi[64][40];
    __shared__ bf16 Bs_lo[64][40];

    const int tid = threadIdx.x;
    const int ln = tid & 63, wv = tid >> 6;
    const int quad = ln >> 4, l16 = ln & 15;
    const int wm = wv >> 1, wn = wv & 1;
    const int n0 = blockIdx.x * 64, m0 = blockIdx.y * 128;

    f32x4 acc[4][2];
#pragma unroll
    for (int i = 0; i < 4; ++i)
#pragma unroll
        for (int j = 0; j < 2; ++j) acc[i][j] = (f32x4){0.f, 0.f, 0.f, 0.f};

    const int sra = tid >> 1, sca = (tid & 1) << 4;  // A: 128 rows x 32 cols
    const int srb = tid >> 2, scb = (tid & 3) << 3;  // B: 64 rows x 32 cols
    const float* gA = ctx + (size_t)(m0 + sra) * HIDDEN + sca;
    const bf16* gBh = Bhi + (size_t)(n0 + srb) * HIDDEN + scb;
    const bf16* gBl = Blo + (size_t)(n0 + srb) * HIDDEN + scb;

    float fa[16];
    bf16x8 brh, brl;
#pragma unroll
    for (int j = 0; j < 4; ++j) *(float4*)&fa[4 * j] = *(const float4*)(gA + 4 * j);
    brh = *(const bf16x8*)gBh;
    brl = *(const bf16x8*)gBl;

    for (int k0 = 0; k0 < HIDDEN; k0 += 32) {
        bf16 hi[16], lo[16];
#pragma unroll
        for (int j = 0; j < 16; ++j) {
            hi[j] = (bf16)fa[j];
            lo[j] = (bf16)(fa[j] - (float)hi[j]);
        }
        __syncthreads();
        *(bf16x8*)&As_hi[sra][sca] = *(bf16x8*)&hi[0];
        *(bf16x8*)&As_hi[sra][sca + 8] = *(bf16x8*)&hi[8];
        *(bf16x8*)&As_lo[sra][sca] = *(bf16x8*)&lo[0];
        *(bf16x8*)&As_lo[sra][sca + 8] = *(bf16x8*)&lo[8];
        *(bf16x8*)&Bs_hi[srb][scb] = brh;
        *(bf16x8*)&Bs_lo[srb][scb] = brl;
        __syncthreads();
        if (k0 + 32 < HIDDEN) {
#pragma unroll
            for (int j = 0; j < 4; ++j)
                *(float4*)&fa[4 * j] = *(const float4*)(gA + k0 + 32 + 4 * j);
            brh = *(const bf16x8*)(gBh + k0 + 32);
            brl = *(const bf16x8*)(gBl + k0 + 32);
        }

        bf16x8 ah[4], al[4], bh[2], bl[2];
#pragma unroll
        for (int i = 0; i < 4; ++i) {
            ah[i] = *(bf16x8*)&As_hi[wm * 64 + i * 16 + l16][quad * 8];
            al[i] = *(bf16x8*)&As_lo[wm * 64 + i * 16 + l16][quad * 8];
        }
#pragma unroll
        for (int i = 0; i < 2; ++i) {
            bh[i] = *(bf16x8*)&Bs_hi[wn * 32 + i * 16 + l16][quad * 8];
            bl[i] = *(bf16x8*)&Bs_lo[wn * 32 + i * 16 + l16][quad * 8];
        }
#pragma unroll
        for (int mi = 0; mi < 4; ++mi)
#pragma unroll
            for (int ni = 0; ni < 2; ++ni) {
                f32x4 c = acc[mi][ni];
                c = __builtin_amdgcn_mfma_f32_16x16x32_bf16(ah[mi], bh[ni], c, 0, 0, 0);
                c = __builtin_amdgcn_mfma_f32_16x16x32_bf16(ah[mi], bl[ni], c, 0, 0, 0);
                c = __builtin_amdgcn_mfma_f32_16x16x32_bf16(al[mi], bh[ni], c, 0, 0, 0);
                acc[mi][ni] = c;
            }
    }

#pragma unroll
    for (int ni = 0; ni < 2; ++ni) {
        const int n = n0 + wn * 32 + ni * 16 + l16;
        const float bb = bo[n];
#pragma unroll
        for (int mi = 0; mi < 4; ++mi)
#pragma unroll
            for (int r = 0; r < 4; ++r) {
                const int m = m0 + wm * 64 + mi * 16 + quad * 4 + r;
                float x = acc[mi][ni][r] + bb;
                x = 0.5f * x * (1.0f + erff(x * 0.70710678118654752440f));
                fout[(size_t)m * HIDDEN + n] = x;
            }
    }
}

// ---------------------------------------------------------------------------
extern "C" void kernel_launch(void* const* d_in, const int* in_sizes, int n_in,
                              void* d_out, int out_size, void* d_ws, size_t ws_size,
                              hipStream_t stream) {
    const float* X    = (const float*)d_in[0];
    const float* mask = (const float*)d_in[1];
    const float* Wq   = (const float*)d_in[2];
    const float* bq   = (const float*)d_in[3];
    const float* Wk   = (const float*)d_in[4];
    const float* bk   = (const float*)d_in[5];
    const float* Wv   = (const float*)d_in[6];
    const float* bv   = (const float*)d_in[7];
    const float* Wo   = (const float*)d_in[8];
    const float* bo   = (const float*)d_in[9];
    float* out = (float*)d_out;

    char* w = (char*)d_ws;
    const size_t NE = (size_t)BATCH * SEQ * HIDDEN;  // 6.29M elems
    bf16* q_ws   = (bf16*)w;  w += NE * 2;
    bf16* k_ws   = (bf16*)w;  w += NE * 2;
    bf16* vt_ws  = (bf16*)w;  w += NE * 2;
    float* ctx   = (float*)w; w += NE * 4;
    bf16* Xb     = (bf16*)w;  w += NE * 2;
    bf16* Wt     = (bf16*)w;  w += (size_t)3 * HIDDEN * HIDDEN * 2;
    bf16* Wot_hi = (bf16*)w;  w += (size_t)HIDDEN * HIDDEN * 2;
    bf16* Wot_lo = (bf16*)w;  w += (size_t)HIDDEN * HIDDEN * 2;

    prep_x<<<(int)(NE / 2048), 256, 0, stream>>>(X, Xb);
    prep_w<<<dim3(12, 12, 4), 256, 0, stream>>>(Wq, Wk, Wv, Wo, Wt, Wot_hi,
                                                Wot_lo);
    gemm_qkv<<<dim3(18, 64), 256, 0, stream>>>(Xb, Wt, bq, bk, bv, q_ws, k_ws,
                                               vt_ws);
    attn_mfma<<<dim3(16 * NH * BATCH), 256, 0, stream>>>(q_ws, k_ws, vt_ws,
                                                         mask, ctx);
    gemm_out<<<dim3(12, 64), 256, 0, stream>>>(ctx, Wot_hi, Wot_lo, bo, out);
}